// Round 9
// baseline (507.481 us; speedup 1.0000x reference)
//
#include <hip/hip_runtime.h>

// DiffeomorphicLearnerTorch, R9: barrier-free wave-autonomous flash kernel
// (R8 with the zj tile-stride bug fixed: one jblk = 8192 ushorts per 32-j tile;
// R8 strode 2 jblks -> wrong tiles + OOB reads into erow -> NaN).
// Per step: Z += DT*(Z@Aaff^T + b + [ei*ej*exp(2*C1*Z@Z^T)]@A_t)
// Design: swap operand order in BOTH gemms (S^T = Zj@Zi^T; O^T = At^T@P^T) so
// P^T's B-fragment is built in-register from S^T's C-layout via v_perm packs +
// __shfl_xor(32) + lhi-select. Every wave: GEMM1 (2 indep S chains) -> exp ->
// transpose-pack -> GEMM2 (4 indep O chains). NO __syncthreads anywhere.
// Epilogue: wave-private LDS bounce (no barrier) for coalesced O stores.
// GEMM1 duplicated x2 (per d-half) = 25.8 GF/dispatch vs 17.2 ideal.
// Frag-linear layouts (verified R4-R7):
//   Zf  [128 u][16 ks][64 lane]x8 bf16  (A- and B-operand frags of Z rows)
//   ATf [t][8 db][256 jb16][64 lane]x8 bf16 (A-operand frags of A_t^T)

#define N_PTS 4096
#define DIM   256
#define DT_C  0.125f
#define C1    (1.0f/512.0f)

typedef __bf16 bf16x8 __attribute__((ext_vector_type(8)));
typedef float  f32x16 __attribute__((ext_vector_type(16)));
typedef float  f32x4v __attribute__((ext_vector_type(4)));
typedef unsigned int   u32x4 __attribute__((ext_vector_type(4)));
typedef unsigned short u16x8 __attribute__((ext_vector_type(8)));

__device__ __forceinline__ unsigned short f2bf(float f) {
  unsigned int u = __builtin_bit_cast(unsigned int, f);
  u += 0x7fffu + ((u >> 16) & 1u);          // RNE
  return (unsigned short)(u >> 16);
}
__device__ __forceinline__ float bf2f(unsigned short s) {
  unsigned int u = ((unsigned int)s) << 16;
  return __builtin_bit_cast(float, u);
}
// pack two f32 -> two bf16 (truncate; P is a low-precision intermediate)
__device__ __forceinline__ unsigned int packtr(float lo, float hi) {
  return __builtin_amdgcn_perm(__builtin_bit_cast(unsigned int, hi),
                               __builtin_bit_cast(unsigned int, lo), 0x07060302u);
}

// ---- ATf: A[t][4096][256] f32 -> frag-linear bf16 tiles ----
__global__ __launch_bounds__(256) void k_prep(const float* __restrict__ A,
                                              unsigned short* __restrict__ ATf) {
  __shared__ float sT[64][36];
  const int jgrp = blockIdx.x, ds = blockIdx.y, t = blockIdx.z;
  const int tid = threadIdx.x;
  const float* Ab = A + (size_t)t * N_PTS * DIM;
  {
    const int j_l = tid >> 2, dq = tid & 3;
    const float* src = Ab + (size_t)(jgrp * 64 + j_l) * DIM + ds * 32 + dq * 8;
    f32x4v v0 = *(const f32x4v*)src, v1 = *(const f32x4v*)(src + 4);
    *(f32x4v*)&sT[j_l][dq * 8] = v0;
    *(f32x4v*)&sT[j_l][dq * 8 + 4] = v1;
  }
  __syncthreads();
  const int jb_l = tid >> 6, l = tid & 63, l31 = l & 31, lhi = l >> 5;
  u16x8 o;
#pragma unroll
  for (int e = 0; e < 8; ++e) o[e] = f2bf(sT[jb_l * 16 + lhi * 8 + e][l31]);
  unsigned short* dst = ATf + (size_t)t * (8 * 256 * 64 * 8)
                      + ((size_t)(ds * 256 + jgrp * 4 + jb_l) * 64 + l) * 8;
  *(u16x8*)dst = o;
}

// ---- init: X -> Zf frags + erow ----
__global__ __launch_bounds__(256) void k_init(const float* __restrict__ X,
                                              unsigned short* __restrict__ Zf,
                                              float* __restrict__ erow) {
  const int tid = threadIdx.x;
  const int r = blockIdx.x * 8 + (tid >> 5), o = tid & 31;
  const size_t base = (size_t)r * DIM + o * 8;
  f32x4v z0 = *(const f32x4v*)(X + base), z1 = *(const f32x4v*)(X + base + 4);
  u16x8 zb; float s = 0.f;
#pragma unroll
  for (int i = 0; i < 4; ++i) { zb[i] = f2bf(z0[i]); zb[4 + i] = f2bf(z1[i]);
                                s += z0[i] * z0[i] + z1[i] * z1[i]; }
  *(u16x8*)(Zf + ((size_t)((r >> 5) * 16 + (o >> 1)) * 64 + (o & 1) * 32 + (r & 31)) * 8) = zb;
#pragma unroll
  for (int d = 16; d > 0; d >>= 1) s += __shfl_down(s, d, 32);
  if (o == 0) erow[r] = __expf(-s * C1);
}

// ---- fused flash, barrier-free ----
// grid (8 chunks, 64 i-blocks of 64 rows), 256 thr = 4 waves.
// wave (isub=wid&1, dh=wid>>1): output tile O^T[128 d][32 i], j over chunk's 512.
__global__ __launch_bounds__(256, 2) void k_flash(
    const unsigned short* __restrict__ Zf, const float* __restrict__ erow,
    const unsigned short* __restrict__ ATf_t,
    const float* __restrict__ Aaff_t,
    unsigned short* __restrict__ Opart) {
  __shared__ __align__(16) unsigned short bounce[4][32 * 136];  // 34.8KB

  const int tid = threadIdx.x, lane = tid & 63, wid = tid >> 6;
  const int l31 = lane & 31, lhi = lane >> 5;
  const int isub = wid & 1, dh = wid >> 1;
  const int chunk = blockIdx.x;
  const int i0 = blockIdx.y * 64;

  // resident Zi fragments (B-operand for GEMM1, lane=i): 64 VGPRs
  bf16x8 zi[16];
  {
    const unsigned short* zp = Zf + ((size_t)(blockIdx.y * 2 + isub) * 16 * 64 + lane) * 8;
#pragma unroll
    for (int ks = 0; ks < 16; ++ks)
      zi[ks] = __builtin_bit_cast(bf16x8, *(const u32x4*)(zp + ks * 512));
  }
  const float ei = erow[i0 + isub * 32 + l31];   // lane-scalar (i on lanes)

  f32x16 Op[4];
#pragma unroll
  for (int d = 0; d < 4; ++d)
#pragma unroll
    for (int i = 0; i < 16; ++i) Op[d][i] = 0.f;

  // affine: Op[d][i] += Aaff[d][k] * Z[i][k], k-slices ksg = chunk*2 + {0,1}
#pragma unroll
  for (int q = 0; q < 2; ++q) {
    const int ksg = chunk * 2 + q;
    bf16x8 bzi = zi[ksg];
#pragma unroll
    for (int dblk = 0; dblk < 4; ++dblk) {
      const int d = dh * 128 + dblk * 32 + l31;
      const float* ap = Aaff_t + (size_t)d * DIM + ksg * 16 + lhi * 8;
      f32x4v f0 = *(const f32x4v*)ap, f1 = *(const f32x4v*)(ap + 4);
      u16x8 tb;
#pragma unroll
      for (int i = 0; i < 4; ++i) { tb[i] = f2bf(f0[i]); tb[4 + i] = f2bf(f1[i]); }
      Op[dblk] = __builtin_amdgcn_mfma_f32_32x32x16_bf16(
          __builtin_bit_cast(bf16x8, tb), bzi, Op[dblk], 0, 0, 0);
    }
  }

  const unsigned short* zjbase = Zf + ((size_t)(chunk * 16) * 16 * 64 + lane) * 8;
  const unsigned short* atbase = ATf_t + ((size_t)(dh * 4 * 256 + chunk * 32) * 64 + lane) * 8;
  const float* ejbase = erow + chunk * 512 + 4 * lhi;

  u32x4 zj[8], at[8];
  u32x4 B0 = {0, 0, 0, 0}, B1 = {0, 0, 0, 0};
  // prologue: zj ks0-7 of tile 0
#pragma unroll
  for (int k = 0; k < 8; ++k) zj[k] = *(const u32x4*)(zjbase + (size_t)k * 512);

#pragma unroll 1
  for (int n = 0; n < 16; ++n) {
    // GEMM2' of tile n-1 (4 independent O chains)
    if (n) {
      bf16x8 bb0 = __builtin_bit_cast(bf16x8, B0);
      bf16x8 bb1 = __builtin_bit_cast(bf16x8, B1);
#pragma unroll
      for (int dblk = 0; dblk < 4; ++dblk)
        Op[dblk] = __builtin_amdgcn_mfma_f32_32x32x16_bf16(
            __builtin_bit_cast(bf16x8, at[dblk * 2]), bb0, Op[dblk], 0, 0, 0);
#pragma unroll
      for (int dblk = 0; dblk < 4; ++dblk)
        Op[dblk] = __builtin_amdgcn_mfma_f32_32x32x16_bf16(
            __builtin_bit_cast(bf16x8, at[dblk * 2 + 1]), bb1, Op[dblk], 0, 0, 0);
    }
    // hoist ATf A-frags for tile n (consumed next iteration)
#pragma unroll
    for (int dblk = 0; dblk < 4; ++dblk)
#pragma unroll
      for (int s = 0; s < 2; ++s)
        at[dblk * 2 + s] = *(const u32x4*)(atbase +
            ((size_t)dblk * 256 + n * 2 + s) * 512);

    // GEMM1: S^T = Zj @ Zi^T, two independent 8-chains (tile n = jblk n)
    f32x16 Sa, Sb;
#pragma unroll
    for (int i = 0; i < 16; ++i) { Sa[i] = 0.f; Sb[i] = 0.f; }
    {
      const unsigned short* zt = zjbase + (size_t)n * 8192;   // <-- R8 bug fixed
#pragma unroll
      for (int k = 0; k < 8; ++k)
        Sa = __builtin_amdgcn_mfma_f32_32x32x16_bf16(
            __builtin_bit_cast(bf16x8, zj[k]), zi[k], Sa, 0, 0, 0);
      // reload ks8-15 of tile n
#pragma unroll
      for (int k = 0; k < 8; ++k) zj[k] = *(const u32x4*)(zt + (size_t)(8 + k) * 512);
#pragma unroll
      for (int k = 0; k < 8; ++k)
        Sb = __builtin_amdgcn_mfma_f32_32x32x16_bf16(
            __builtin_bit_cast(bf16x8, zj[k]), zi[k + 8], Sb, 0, 0, 0);
      // prefetch zj ks0-7 of tile n+1
      if (n < 15) {
#pragma unroll
        for (int k = 0; k < 8; ++k)
          zj[k] = *(const u32x4*)(zt + (size_t)(16 + k) * 512);
      }
    }
    // P^T[j][i] = ei*ej*exp(2*C1*S^T): build GEMM2' B-frags in-register
    {
      unsigned int G[8];
#pragma unroll
      for (int g = 0; g < 4; ++g) {
        f32x4v ejv = *(const f32x4v*)(ejbase + n * 32 + 8 * g);
#pragma unroll
        for (int p = 0; p < 2; ++p) {
          const int c = g * 4 + p * 2;
          float p0 = ei * ejv[p * 2]     * __expf(2.f * C1 * (Sa[c] + Sb[c]));
          float p1 = ei * ejv[p * 2 + 1] * __expf(2.f * C1 * (Sa[c + 1] + Sb[c + 1]));
          G[g * 2 + p] = packtr(p0, p1);
        }
      }
      unsigned int Gp[8];
#pragma unroll
      for (int r = 0; r < 8; ++r) Gp[r] = __shfl_xor((int)G[r], 32);
      B0[0] = lhi ? Gp[2] : G[0];  B0[1] = lhi ? Gp[3] : G[1];
      B0[2] = lhi ? G[2] : Gp[0];  B0[3] = lhi ? G[3] : Gp[1];
      B1[0] = lhi ? Gp[6] : G[4];  B1[1] = lhi ? Gp[7] : G[5];
      B1[2] = lhi ? G[6] : Gp[4];  B1[3] = lhi ? G[7] : Gp[5];
    }
  }
  // final GEMM2' (tile 15)
  {
    bf16x8 bb0 = __builtin_bit_cast(bf16x8, B0);
    bf16x8 bb1 = __builtin_bit_cast(bf16x8, B1);
#pragma unroll
    for (int dblk = 0; dblk < 4; ++dblk)
      Op[dblk] = __builtin_amdgcn_mfma_f32_32x32x16_bf16(
          __builtin_bit_cast(bf16x8, at[dblk * 2]), bb0, Op[dblk], 0, 0, 0);
#pragma unroll
    for (int dblk = 0; dblk < 4; ++dblk)
      Op[dblk] = __builtin_amdgcn_mfma_f32_32x32x16_bf16(
          __builtin_bit_cast(bf16x8, at[dblk * 2 + 1]), bb1, Op[dblk], 0, 0, 0);
  }

  // epilogue: O^T (d on regs, i on lanes) -> wave-private LDS bounce -> stores
  {
    unsigned short* bw = &bounce[wid][0];
#pragma unroll
    for (int dblk = 0; dblk < 4; ++dblk)
#pragma unroll
      for (int p = 0; p < 8; ++p) {
        const int c = 2 * p;
        const int dloc = dblk * 32 + 4 * lhi + (c & 3) + 8 * (c >> 2);
        unsigned int v = (unsigned int)f2bf(Op[dblk][c]) |
                         ((unsigned int)f2bf(Op[dblk][c + 1]) << 16);
        *(unsigned int*)(bw + l31 * 136 + dloc) = v;
      }
    unsigned short* ob = Opart + (size_t)chunk * N_PTS * DIM;
#pragma unroll
    for (int p = 0; p < 8; ++p) {
      const int row = p * 4 + (lane >> 4);
      const int col = (lane & 15) * 8;
      u32x4 v = *(const u32x4*)(bw + row * 136 + col);
      *(u32x4*)(ob + (size_t)(i0 + isub * 32 + row) * DIM + dh * 128 + col) = v;
    }
  }
}

// ---- update: Z += DT*(sum partials + baff); emit Zf frags + erow ----
__global__ __launch_bounds__(256) void k_update(const float* __restrict__ Zin,
                                                const unsigned short* __restrict__ Opart,
                                                const float* __restrict__ baff_t,
                                                float* __restrict__ Zout,
                                                unsigned short* __restrict__ Zf,
                                                float* __restrict__ erow) {
  const int tid = threadIdx.x;
  const int r = blockIdx.x * 8 + (tid >> 5), o = tid & 31;
  const size_t base = (size_t)r * DIM + o * 8;
  f32x4v z0 = *(const f32x4v*)(Zin + base), z1 = *(const f32x4v*)(Zin + base + 4);
  f32x4v s0 = *(const f32x4v*)(baff_t + o * 8), s1 = *(const f32x4v*)(baff_t + o * 8 + 4);
#pragma unroll
  for (int c = 0; c < 8; ++c) {
    u16x8 p = *(const u16x8*)(Opart + (size_t)c * N_PTS * DIM + base);
#pragma unroll
    for (int i = 0; i < 4; ++i) { s0[i] += bf2f(p[i]); s1[i] += bf2f(p[4 + i]); }
  }
  u16x8 zb; float sv = 0.f;
#pragma unroll
  for (int i = 0; i < 4; ++i) {
    z0[i] += DT_C * s0[i]; z1[i] += DT_C * s1[i];
    zb[i] = f2bf(z0[i]); zb[4 + i] = f2bf(z1[i]);
    sv += z0[i] * z0[i] + z1[i] * z1[i];
  }
  *(f32x4v*)(Zout + base) = z0;
  *(f32x4v*)(Zout + base + 4) = z1;
  *(u16x8*)(Zf + ((size_t)((r >> 5) * 16 + (o >> 1)) * 64 + (o & 1) * 32 + (r & 31)) * 8) = zb;
#pragma unroll
  for (int d = 16; d > 0; d >>= 1) sv += __shfl_down(sv, d, 32);
  if (o == 0) erow[r] = __expf(-sv * C1);
}

extern "C" void kernel_launch(void* const* d_in, const int* in_sizes, int n_in,
                              void* d_out, int out_size, void* d_ws, size_t ws_size,
                              hipStream_t stream) {
  const float* X    = (const float*)d_in[0];
  const float* A    = (const float*)d_in[1];
  const float* Aaff = (const float*)d_in[2];
  const float* baff = (const float*)d_in[3];
  float* out = (float*)d_out;

  char* w = (char*)d_ws;
  size_t off = 0;
  unsigned short* ATf = (unsigned short*)(w + off); off += (size_t)8 * 8 * 256 * 64 * 8 * 2; // 16 MiB
  unsigned short* Zf  = (unsigned short*)(w + off); off += (size_t)N_PTS * DIM * 2;          // 2 MiB
  float* erow = (float*)(w + off); off += (size_t)N_PTS * 4;
  float* Zf32 = (float*)(w + off); off += (size_t)N_PTS * DIM * 4;                           // 4 MiB
  unsigned short* Opart = (unsigned short*)(w + off); off += (size_t)8 * N_PTS * DIM * 2;    // 16 MiB
  (void)ws_size; (void)in_sizes; (void)n_in; (void)out_size;

  k_prep<<<dim3(64, 8, 8), 256, 0, stream>>>(A, ATf);
  k_init<<<512, 256, 0, stream>>>(X, Zf, erow);

  const float* zin = X;
  for (int t = 0; t < 8; ++t) {
    float* zout = (t == 7) ? out : Zf32;  // in-place safe after t=0
    k_flash<<<dim3(8, 64), 256, 0, stream>>>(
        Zf, erow, ATf + (size_t)t * (8 * 256 * 64 * 8), Aaff + (size_t)t * DIM * DIM, Opart);
    k_update<<<512, 256, 0, stream>>>(zin, Opart, baff + (size_t)t * DIM, zout, Zf, erow);
    zin = zout;
  }
}